// Round 7
// baseline (55.419 us; speedup 1.0000x reference)
//
#include <hip/hip_runtime.h>
#include <math.h>

// Problem constants (D_IN == D_OUT == 4096)
constexpr int   D     = 4096;
constexpr float ALPHA = 0.001f;   // heb_lr
constexpr float GAMMA = 0.99f;
constexpr float EPSC  = 0.0001f;

// Decomposition: 16-row chunks. K1: one block per chunk (full width).
constexpr int RCH    = 16;             // rows per chunk
constexpr int NCHUNK = D / RCH;        // 256
constexpr int NGRP   = 16;             // chunk groups for 2-level prefix
constexpr int GSZ    = NCHUNK / NGRP;  // 16 chunks per group
// K3 tiling
constexpr int TPB3 = 256;
constexpr int CPB3 = TPB3 * 4;         // 1024 cols per block
constexpr int NCT3 = D / CPB3;         // 4 column tiles

using vf4 = float __attribute__((ext_vector_type(4)));

// ---------------------------------------------------------------------------
// K1: fused GEMV + chunk partials (in z-units; no global max needed).
// Block c owns rows k0..k0+15 across ALL columns. Phase 1: wave w computes
// row k0+w's full dot product (coalesced float4), z = relu(u+b)^2 to LDS.
// Phase 2: thread-per-float4-column re-reads the block's own 256 KB tile
// (L2/L3-hot) and emits P[c,j] = sum_k z[k] * W[k,j]. W read from HBM once.
// ---------------------------------------------------------------------------
__global__ __launch_bounds__(1024) void k_gp(const float* __restrict__ W,
                                             const float* __restrict__ x,
                                             const float* __restrict__ b,
                                             float* __restrict__ z_out,
                                             float* __restrict__ P) {
    const int tid  = threadIdx.x;
    const int wv   = tid >> 6;            // 0..15 (wave = row)
    const int lane = tid & 63;
    const int c    = blockIdx.x;
    const int k0   = c * RCH;

    __shared__ float sz[RCH];

    // Phase 1: wave wv -> full dot of row k0+wv.
    {
        const int row = k0 + wv;
        const float4* Wr = reinterpret_cast<const float4*>(W + (size_t)row * D);
        const float4* xv = reinterpret_cast<const float4*>(x);
        float acc = 0.f;
        #pragma unroll
        for (int it = 0; it < D / 256; ++it) {    // 16: 64 lanes x float4
            const float4 a  = Wr[lane + it * 64];
            const float4 xx = xv[lane + it * 64];
            acc += a.x * xx.x + a.y * xx.y + a.z * xx.z + a.w * xx.w;
        }
        #pragma unroll
        for (int off = 32; off; off >>= 1) acc += __shfl_down(acc, off, 64);
        if (lane == 0) {
            const float u = acc + b[row];
            const float r = fmaxf(u, 0.f);
            sz[wv] = r * r;                        // z = relu(u)^2 (LAMB=2)
        }
    }
    __syncthreads();
    if (tid < RCH) z_out[k0 + tid] = sz[tid];

    // Phase 2: column partials from the just-read (cache-hot) tile.
    {
        const float4* Wc = reinterpret_cast<const float4*>(W + (size_t)k0 * D) + tid;
        float4 acc = make_float4(0.f, 0.f, 0.f, 0.f);
        #pragma unroll
        for (int k = 0; k < RCH; ++k) {
            const float zv = sz[k];
            const float4 w = Wc[(size_t)k * (D / 4)];
            acc.x += zv * w.x; acc.y += zv * w.y;
            acc.z += zv * w.z; acc.w += zv * w.w;
        }
        reinterpret_cast<float4*>(P + (size_t)c * D)[tid] = acc;
    }
}

// ---------------------------------------------------------------------------
// K2: group super-sums SS[g,j] = sum of 16 chunk partials. Fully parallel,
// no serial chain (avoids the R1/R2 scan-latency trap). 4 MB read, 256 KB out.
// ---------------------------------------------------------------------------
__global__ __launch_bounds__(256) void k_ss(const float* __restrict__ P,
                                            float* __restrict__ SS) {
    const int j4 = blockIdx.x * 256 + threadIdx.x;   // float4 column 0..1023
    const int g  = blockIdx.y;                        // group 0..15
    const float4* Pp = reinterpret_cast<const float4*>(P)
                     + (size_t)(g * GSZ) * (D / 4) + j4;
    float4 a = make_float4(0.f, 0.f, 0.f, 0.f);
    #pragma unroll
    for (int i = 0; i < GSZ; ++i) {
        const float4 p = Pp[(size_t)i * (D / 4)];
        a.x += p.x; a.y += p.y; a.z += p.z; a.w += p.w;
    }
    reinterpret_cast<float4*>(SS)[(size_t)g * (D / 4) + j4] = a;
}

// ---------------------------------------------------------------------------
// K3: redundant stats (identical reduction order across blocks) + two-level
// exclusive prefix (SS groups + intra-group P rows, <=30 rows, L2-resident)
// + in-chunk inclusive scan + Hebbian delta + sign-split decay. W2 nt-stored.
// ---------------------------------------------------------------------------
__global__ __launch_bounds__(TPB3) void k_update(const float* __restrict__ W,
                                                 const float* __restrict__ x,
                                                 const float* __restrict__ z,
                                                 const float* __restrict__ ea,
                                                 const float* __restrict__ P,
                                                 const float* __restrict__ SS,
                                                 float* __restrict__ y_out,
                                                 float* __restrict__ ea_out,
                                                 float* __restrict__ W2) {
    const int tid  = threadIdx.x;
    const int t    = blockIdx.x;
    const int c    = blockIdx.y;
    const int j4   = t * TPB3 + tid;          // float4 column index
    const int k0   = c * RCH;
    const int wv   = tid >> 6;
    const int lane = tid & 63;

    __shared__ float sred[4];
    __shared__ float sm[2];                   // m^2, sum(ea_new)
    __shared__ float sy[RCH], sgp[RCH], sgn[RCH];

    // stats pass 1: m^2 = max(z)  (square is monotone on relu output)
    float lmax = 0.f;
    #pragma unroll
    for (int i = 0; i < D / TPB3; ++i)
        lmax = fmaxf(lmax, z[i * TPB3 + tid]);
    #pragma unroll
    for (int off = 32; off; off >>= 1) lmax = fmaxf(lmax, __shfl_down(lmax, off, 64));
    if (lane == 0) sred[wv] = lmax;
    __syncthreads();
    if (tid == 0) sm[0] = fmaxf(fmaxf(sred[0], sred[1]), fmaxf(sred[2], sred[3]));
    __syncthreads();
    const float inv_m2 = 1.f / sm[0];

    // stats pass 2: sum(ea_new)
    float lsum = 0.f;
    #pragma unroll
    for (int i = 0; i < D / TPB3; ++i) {
        const int r = i * TPB3 + tid;
        lsum += GAMMA * ea[r] + (1.f - GAMMA) * (z[r] * inv_m2);
    }
    #pragma unroll
    for (int off = 32; off; off >>= 1) lsum += __shfl_down(lsum, off, 64);
    if (lane == 0) sred[wv] = lsum;           // safe: all passed prior sync
    __syncthreads();
    if (tid == 0) sm[1] = (sred[0] + sred[1]) + (sred[2] + sred[3]);
    __syncthreads();
    const float inv_avg = (float)D / sm[1];

    // own-chunk y / gf; (c, t==0) blocks write y / ea globals
    if (tid < RCH) {
        const int r = k0 + tid;
        const float yv = z[r] * inv_m2;
        const float ev = GAMMA * ea[r] + (1.f - GAMMA) * yv;
        const float a  = ev * inv_avg;
        const float g  = EPSC * tanhf(-EPSC * (a - 1.f)) + 1.f;
        sy[tid]  = yv;
        sgp[tid] = g;
        sgn[tid] = 1.f / g;
        if (t == 0) { y_out[r] = yv; ea_out[r] = ev; }
    }
    __syncthreads();

    // two-level exclusive prefix (z-units): full groups then intra-group rows
    const int g = c >> 4;                      // GSZ == 16
    float4 a0 = make_float4(0.f, 0.f, 0.f, 0.f);
    float4 a1 = make_float4(0.f, 0.f, 0.f, 0.f);
    {
        const float4* SSp = reinterpret_cast<const float4*>(SS) + j4;
        int i = 0;
        #pragma unroll 4
        for (; i + 2 <= g; i += 2) {
            const float4 p0 = SSp[(size_t)i * (D / 4)];
            const float4 p1 = SSp[(size_t)(i + 1) * (D / 4)];
            a0.x += p0.x; a0.y += p0.y; a0.z += p0.z; a0.w += p0.w;
            a1.x += p1.x; a1.y += p1.y; a1.z += p1.z; a1.w += p1.w;
        }
        if (i < g) {
            const float4 p0 = SSp[(size_t)i * (D / 4)];
            a0.x += p0.x; a0.y += p0.y; a0.z += p0.z; a0.w += p0.w;
        }
    }
    {
        const float4* Pp = reinterpret_cast<const float4*>(P) + j4;
        int i = g * GSZ;
        #pragma unroll 4
        for (; i + 2 <= c; i += 2) {
            const float4 p0 = Pp[(size_t)i * (D / 4)];
            const float4 p1 = Pp[(size_t)(i + 1) * (D / 4)];
            a0.x += p0.x; a0.y += p0.y; a0.z += p0.z; a0.w += p0.w;
            a1.x += p1.x; a1.y += p1.y; a1.z += p1.z; a1.w += p1.w;
        }
        if (i < c) {
            const float4 p0 = Pp[(size_t)i * (D / 4)];
            a0.x += p0.x; a0.y += p0.y; a0.z += p0.z; a0.w += p0.w;
        }
    }
    // convert prefix to y-units once
    float4 s;
    s.x = (a0.x + a1.x) * inv_m2; s.y = (a0.y + a1.y) * inv_m2;
    s.z = (a0.z + a1.z) * inv_m2; s.w = (a0.w + a1.w) * inv_m2;

    const float4 xv = reinterpret_cast<const float4*>(x)[j4];
    const float4* Wp  = reinterpret_cast<const float4*>(W  + (size_t)k0 * D) + j4;
    float4*       W2p = reinterpret_cast<float4*>(W2 + (size_t)k0 * D) + j4;
    #pragma unroll
    for (int k = 0; k < RCH; ++k) {
        const float yv = sy[k];
        const float gp = sgp[k];
        const float gn = sgn[k];
        const float4 w = Wp[(size_t)k * (D / 4)];
        s.x += yv * w.x; s.y += yv * w.y;
        s.z += yv * w.z; s.w += yv * w.w;
        vf4 o;
        {
            const float w1 = w.x + ALPHA * (yv * xv.x - yv * s.x);
            o.x = w1 * (w1 > 0.f ? gp : gn);   // == sign-split (0 stays 0)
        }
        {
            const float w1 = w.y + ALPHA * (yv * xv.y - yv * s.y);
            o.y = w1 * (w1 > 0.f ? gp : gn);
        }
        {
            const float w1 = w.z + ALPHA * (yv * xv.z - yv * s.z);
            o.z = w1 * (w1 > 0.f ? gp : gn);
        }
        {
            const float w1 = w.w + ALPHA * (yv * xv.w - yv * s.w);
            o.w = w1 * (w1 > 0.f ? gp : gn);
        }
        __builtin_nontemporal_store(o, reinterpret_cast<vf4*>(W2p + (size_t)k * (D / 4)));
    }
}

// ---------------------------------------------------------------------------
extern "C" void kernel_launch(void* const* d_in, const int* in_sizes, int n_in,
                              void* d_out, int out_size, void* d_ws, size_t ws_size,
                              hipStream_t stream) {
    const float* x  = (const float*)d_in[0];
    const float* W  = (const float*)d_in[1];
    const float* b  = (const float*)d_in[2];
    const float* ea = (const float*)d_in[3];

    float* out    = (float*)d_out;
    float* y_out  = out;                        // [D]
    float* W2_out = out + D;                    // [D*D]
    float* ea_out = out + D + (size_t)D * D;    // [D]

    float* ws = (float*)d_ws;
    float* z  = ws;                             // [D]            (16 KB)
    float* P  = ws + D;                         // [NCHUNK * D]   (4 MB)
    float* SS = P + (size_t)NCHUNK * D;         // [NGRP * D]     (256 KB)

    k_gp<<<NCHUNK, 1024, 0, stream>>>(W, x, b, z, P);
    k_ss<<<dim3(4, NGRP), 256, 0, stream>>>(P, SS);
    k_update<<<dim3(NCT3, NCHUNK), TPB3, 0, stream>>>(W, x, z, ea, P, SS,
                                                      y_out, ea_out, W2_out);
}